// Round 8
// baseline (3324.241 us; speedup 1.0000x reference)
//
#include <hip/hip_runtime.h>
#include <stdint.h>

#define BB 512
#define TT 512
#define FF 128
#define UU 256

typedef float f32x4 __attribute__((ext_vector_type(4)));
typedef short short8 __attribute__((ext_vector_type(8)));
typedef int int4v __attribute__((ext_vector_type(4)));
typedef float float4v __attribute__((ext_vector_type(4)));
typedef unsigned short ushort4v __attribute__((ext_vector_type(4)));

__device__ __forceinline__ unsigned short f2bf(float f) {
  union { float f; uint32_t u; } v; v.f = f;
  uint32_t u = v.u;
  u += 0x7fffu + ((u >> 16) & 1u);
  return (unsigned short)(u >> 16);
}
__device__ __forceinline__ float fast_rcp(float x) { return __builtin_amdgcn_rcpf(x); }
__device__ __forceinline__ float sigmoidf_(float x) { return fast_rcp(1.f + __expf(-x)); }
__device__ __forceinline__ float tanhf_(float x) { return 1.f - 2.f * fast_rcp(1.f + __expf(2.f * x)); }

// ---- prep: W^T combined [1024 cols][384 k] bf16, Wo^T [32][256] bf16, zero xch ---------
// xch zeroed with plain stores; kernel-end L2 writeback publishes zeros to HBM/MALL
// (validated in round 5: sc0sc1 readers of a prep-zeroed buffer never saw stale tags).
__global__ void prep_w(const float* __restrict__ Wx, const float* __restrict__ Wh,
                       const float* __restrict__ Wo,
                       unsigned short* __restrict__ Wt, unsigned short* __restrict__ Wot,
                       int* __restrict__ xch) {
  int bidx = blockIdx.x;
  int tid = threadIdx.x; // 384
  if (bidx < 1024) {
    int n = bidx, k = tid;
    float v = (k < FF) ? Wx[(size_t)k * 1024 + n] : Wh[(size_t)(k - FF) * 1024 + n];
    Wt[(size_t)n * 384 + k] = f2bf(v);
  } else if (bidx == 1024) {
    for (int i = tid; i < 32 * 256; i += 384) {
      int o = i >> 8, u = i & 255;
      Wot[o * 256 + u] = f2bf(Wo[(size_t)u * 32 + o]);
    }
  } else {
    int base = (bidx - 1025) * 2048;  // 128 blocks x 2048 dwords = 1 MB
    for (int i = tid; i < 2048; i += 384) xch[base + i] = 0;
  }
}

// ---- x f32 -> bf16 ----------------------------------------------------------------------
__global__ void conv_x(const float* __restrict__ xf, unsigned short* __restrict__ xb) {
  size_t i = (size_t)blockIdx.x * 1024 + (size_t)threadIdx.x * 4;
  float4v v = *(const float4v*)(xf + i);
  ushort4v o;
  o.x = f2bf(v.x); o.y = f2bf(v.y); o.z = f2bf(v.z); o.w = f2bf(v.w);
  *(ushort4v*)(xb + i) = o;
}

__device__ __forceinline__ short8 load_xfrag(const unsigned short* p) {
  return *(const short8*)p;
}
__device__ __forceinline__ short8 load_xfrag(const float* p) {
  float4v lo = *(const float4v*)p;
  float4v hi = *(const float4v*)(p + 4);
  union { short8 v; unsigned short s[8]; } a;
  a.s[0] = f2bf(lo.x); a.s[1] = f2bf(lo.y); a.s[2] = f2bf(lo.z); a.s[3] = f2bf(lo.w);
  a.s[4] = f2bf(hi.x); a.s[5] = f2bf(hi.y); a.s[6] = f2bf(hi.z); a.s[7] = f2bf(hi.w);
  return a.v;
}

__device__ __forceinline__ void store_sc01(int* p, int v) {
  asm volatile("global_store_dword %0, %1, off sc0 sc1" :: "v"(p), "v"(v) : "memory");
}
__device__ __forceinline__ int tchk(const int4v& v, int t) {
  return ((v.x ^ t) | (v.y ^ t) | (v.z ^ t) | (v.w ^ t)) & 0xffff;
}
__device__ __forceinline__ uint32_t pk2(int lo, int hi) {
  return ((uint32_t)lo >> 16) | ((uint32_t)hi & 0xffff0000u);
}
__device__ __forceinline__ short8 pack2(const int4v& a, const int4v& b) {
  int4v k;
  k.x = (int)pk2(a.x, a.y); k.y = (int)pk2(a.z, a.w);
  k.z = (int)pk2(b.x, b.y); k.w = (int)pk2(b.z, b.w);
  return __builtin_bit_cast(short8, k);
}

// poll partner's tagged h tile until all 32 dwords carry tag t; deliver 4 A-frags
__device__ __forceinline__ void poll_hq(const int* pb, int t, short8* hq) {
  int4v a0, a1, a2, a3, a4, a5, a6, a7;
  for (;;) {
    asm volatile(
        "global_load_dwordx4 %0, %8, off sc0 sc1\n\t"
        "global_load_dwordx4 %1, %8, off offset:16 sc0 sc1\n\t"
        "global_load_dwordx4 %2, %8, off offset:128 sc0 sc1\n\t"
        "global_load_dwordx4 %3, %8, off offset:144 sc0 sc1\n\t"
        "global_load_dwordx4 %4, %8, off offset:256 sc0 sc1\n\t"
        "global_load_dwordx4 %5, %8, off offset:272 sc0 sc1\n\t"
        "global_load_dwordx4 %6, %8, off offset:384 sc0 sc1\n\t"
        "global_load_dwordx4 %7, %8, off offset:400 sc0 sc1\n\t"
        "s_waitcnt vmcnt(0)"
        : "=&v"(a0), "=&v"(a1), "=&v"(a2), "=&v"(a3),
          "=&v"(a4), "=&v"(a5), "=&v"(a6), "=&v"(a7)
        : "v"(pb) : "memory");
    int m = tchk(a0, t) | tchk(a1, t) | tchk(a2, t) | tchk(a3, t)
          | tchk(a4, t) | tchk(a5, t) | tchk(a6, t) | tchk(a7, t);
    if (__all(m == 0)) break;
  }
  __builtin_amdgcn_sched_barrier(0);  // keep consumers below the waitcnt (rule #18)
  hq[0] = pack2(a0, a1); hq[1] = pack2(a2, a3);
  hq[2] = pack2(a4, a5); hq[3] = pack2(a6, a7);
}

// ---- recurrent core: 2 CUs per m-tile; Wh in regs; Wx+Wo in LDS; tagged MALL exchange ---
// LDS: [0,128K) Wx frags; [128K,136K) h dbuf (2x4KB, XOR-swizzled); [136K+3K pad...] Wo.
// xch: per (mt, side, slot): [16 rows][128 units] tagged dwords; idx=((mt*2+side)*2+slot)*2048.
template <int HALF, typename XT>
__device__ __forceinline__ void lstm_core(const XT* __restrict__ x,
                                          const unsigned short* __restrict__ Wt,
                                          const unsigned short* __restrict__ Wot,
                                          const float* __restrict__ bvec,
                                          const float* __restrict__ bo,
                                          float* __restrict__ out,
                                          int* __restrict__ xch, int bid, char* lds) {
  const int mt = bid & 31;
  const int tid = threadIdx.x;
  const int w = tid >> 6, l = tid & 63;
  const int lr = l & 15, lhi = l >> 4;
  const int b0 = mt * 16;
  const int uloc = HALF * 128 + w * 16 + lr;  // global unit col in [0,256)
  char* h_lds  = lds + 131072;
  char* wo_lds = lds + 139264;

  // stage Wx fragments (this wave's 16) into LDS — identity map
#pragma unroll
  for (int g = 0; g < 4; ++g)
#pragma unroll
    for (int kk = 0; kk < 4; ++kk) {
      const unsigned short* wp = Wt + (size_t)(g * 256 + uloc) * 384 + kk * 32 + 8 * lhi;
      *(short8*)(lds + ((size_t)((w * 16 + g * 4 + kk) * 64 + l)) * 16) = *(const short8*)wp;
    }
  // stage Wo fragments (shared by all waves): 8 kfrags x 64 lanes x 16B
  if (w == 0) {
#pragma unroll
    for (int kf = 0; kf < 8; ++kf) {
      const unsigned short* wp = Wot + (size_t)(HALF * 16 + lr) * 256 + kf * 32 + 8 * lhi;
      *(short8*)(wo_lds + (size_t)(kf * 64 + l) * 16) = *(const short8*)wp;
    }
  }

  // Wh fragments in registers: Bh[gate][kf], kf 0..7 over all 256 h-units
  short8 Bh[4][8];
#pragma unroll
  for (int g = 0; g < 4; ++g) {
    const unsigned short* wp = Wt + (size_t)(g * 256 + uloc) * 384 + FF + 8 * lhi;
#pragma unroll
    for (int kf = 0; kf < 8; ++kf) Bh[g][kf] = *(const short8*)(wp + kf * 32);
  }
  float bias[4];
#pragma unroll
  for (int g = 0; g < 4; ++g) bias[g] = bvec[g * 256 + uloc];
  const float bob = bo[HALF * 16 + lr];
  float cst[4] = {0.f, 0.f, 0.f, 0.f};

  const int rtile = (mt * 2 + (1 - HALF)) * 2;
  const int wtile = (mt * 2 + HALF) * 2;
  const int roff = lr * 128 + 8 * lhi;

  // prologue: zx(0) = bias + x(0)·Wx
  f32x4 zx[4];
  {
    short8 xa0[4];
    const XT* xp = x + ((size_t)(b0 + lr) * TT + 0) * FF + 8 * lhi;
#pragma unroll
    for (int kk = 0; kk < 4; ++kk) xa0[kk] = load_xfrag(xp + kk * 32);
    __syncthreads();  // staging complete
#pragma unroll
    for (int g = 0; g < 4; ++g) { f32x4 a4 = {bias[g], bias[g], bias[g], bias[g]}; zx[g] = a4; }
#pragma unroll
    for (int kk = 0; kk < 4; ++kk) {
      short8 bx[4];
#pragma unroll
      for (int g = 0; g < 4; ++g)
        bx[g] = *(const short8*)(lds + ((size_t)((w * 16 + g * 4 + kk) * 64 + l)) * 16);
#pragma unroll
      for (int g = 0; g < 4; ++g)
        zx[g] = __builtin_amdgcn_mfma_f32_16x16x32_bf16(xa0[kk], bx[g], zx[g], 0, 0, 0);
    }
  }

#pragma unroll 1
  for (int t = 0; t < TT; ++t) {
    const int cur = t & 1, nxt = cur ^ 1;

    f32x4 acc[4];
#pragma unroll
    for (int g = 0; g < 4; ++g) acc[g] = zx[g];

    // issue x(t+1) loads early; consumed in the zx section below
    short8 xan[4];
    {
      const int tn = (t + 1 < TT) ? t + 1 : t;
      const XT* xp = x + ((size_t)(b0 + lr) * TT + tn) * FF + 8 * lhi;
#pragma unroll
      for (int kk = 0; kk < 4; ++kk) xan[kk] = load_xfrag(xp + kk * 32);
    }

    short8 ho[4], hq[4];
    if (t > 0) {
      // own-half h(t) from LDS dbuf
#pragma unroll
      for (int ko = 0; ko < 4; ++ko) {
        const int byte = cur * 4096 + lr * 256 + ((ko * 64 + lhi * 16) ^ ((lr & 7) << 4));
        ho[ko] = *(const short8*)(h_lds + byte);
      }
#pragma unroll
      for (int ko = 0; ko < 4; ++ko)
#pragma unroll
        for (int g = 0; g < 4; ++g)
          acc[g] = __builtin_amdgcn_mfma_f32_16x16x32_bf16(ho[ko], Bh[g][HALF * 4 + ko], acc[g], 0, 0, 0);

      // partner half: tagged poll (data IS the flag), then MFMAs
      poll_hq(xch + (rtile + cur) * 2048 + roff, t, hq);
#pragma unroll
      for (int kf = 0; kf < 4; ++kf)
#pragma unroll
        for (int g = 0; g < 4; ++g)
          acc[g] = __builtin_amdgcn_mfma_f32_16x16x32_bf16(hq[kf], Bh[g][(1 - HALF) * 4 + kf], acc[g], 0, 0, 0);
    }

    // gates
    unsigned short hs[4];
#pragma unroll
    for (int r = 0; r < 4; ++r) {
      float zi = acc[0][r], zf = acc[1][r], zg = acc[2][r], zo = acc[3][r];
      float si = sigmoidf_(zi), sf = sigmoidf_(zf), so = sigmoidf_(zo);
      float tg = tanhf_(zg);
      float cn = sf * cst[r] + si * tg;
      cst[r] = cn;
      hs[r] = f2bf(so * tanhf_(cn));
    }

    // publish h(t+1): tagged sc0sc1 dwords (no drain, no flag) + LDS own-half
    const int wb = (wtile + nxt) * 2048 + w * 16 + lr;
#pragma unroll
    for (int r = 0; r < 4; ++r) {
      const int row = 4 * lhi + r;
      const int byte = nxt * 4096 + row * 256 + (((w * 16 + lr) * 2) ^ ((row & 7) << 4));
      *(unsigned short*)(h_lds + byte) = hs[r];
      store_sc01(xch + wb + row * 128, ((int)(uint32_t)hs[r] << 16) | (t + 1));
    }

    // ---- slack work (off critical path) ----
    // zx(t+1) = bias + x(t+1)·Wx
#pragma unroll
    for (int g = 0; g < 4; ++g) { f32x4 a4 = {bias[g], bias[g], bias[g], bias[g]}; zx[g] = a4; }
#pragma unroll
    for (int kk = 0; kk < 4; ++kk) {
      short8 bx[4];
#pragma unroll
      for (int g = 0; g < 4; ++g)
        bx[g] = *(const short8*)(lds + ((size_t)((w * 16 + g * 4 + kk) * 64 + l)) * 16);
#pragma unroll
      for (int g = 0; g < 4; ++g)
        zx[g] = __builtin_amdgcn_mfma_f32_16x16x32_bf16(xan[kk], bx[g], zx[g], 0, 0, 0);
    }
    // y(t-1) = h(t)·Wo + bo (this block's 16 output cols)
    if (t > 0) {
      f32x4 yacc = {bob, bob, bob, bob};
#pragma unroll
      for (int ko = 0; ko < 4; ++ko) {
        short8 wo = *(const short8*)(wo_lds + (size_t)((HALF * 4 + ko) * 64 + l) * 16);
        yacc = __builtin_amdgcn_mfma_f32_16x16x32_bf16(ho[ko], wo, yacc, 0, 0, 0);
      }
#pragma unroll
      for (int kf = 0; kf < 4; ++kf) {
        short8 wo = *(const short8*)(wo_lds + (size_t)(((1 - HALF) * 4 + kf) * 64 + l) * 16);
        yacc = __builtin_amdgcn_mfma_f32_16x16x32_bf16(hq[kf], wo, yacc, 0, 0, 0);
      }
#pragma unroll
      for (int r = 0; r < 4; ++r)
        out[((size_t)(b0 + 4 * lhi + r) * TT + (t - 1)) * 32 + HALF * 16 + lr] = yacc[r];
    }

    __syncthreads();
  }

  // epilogue: y(TT-1) from h(TT)  (slot TT&1 == 0, tag TT)
  {
    short8 ho[4], hq[4];
#pragma unroll
    for (int ko = 0; ko < 4; ++ko) {
      const int byte = 0 * 4096 + lr * 256 + ((ko * 64 + lhi * 16) ^ ((lr & 7) << 4));
      ho[ko] = *(const short8*)(h_lds + byte);
    }
    poll_hq(xch + (rtile + 0) * 2048 + roff, TT, hq);
    f32x4 yacc = {bob, bob, bob, bob};
#pragma unroll
    for (int ko = 0; ko < 4; ++ko) {
      short8 wo = *(const short8*)(wo_lds + (size_t)((HALF * 4 + ko) * 64 + l) * 16);
      yacc = __builtin_amdgcn_mfma_f32_16x16x32_bf16(ho[ko], wo, yacc, 0, 0, 0);
    }
#pragma unroll
    for (int kf = 0; kf < 4; ++kf) {
      short8 wo = *(const short8*)(wo_lds + (size_t)(((1 - HALF) * 4 + kf) * 64 + l) * 16);
      yacc = __builtin_amdgcn_mfma_f32_16x16x32_bf16(hq[kf], wo, yacc, 0, 0, 0);
    }
#pragma unroll
    for (int r = 0; r < 4; ++r)
      out[((size_t)(b0 + 4 * lhi + r) * TT + (TT - 1)) * 32 + HALF * 16 + lr] = yacc[r];
  }
}

template <typename XT>
__global__ void __launch_bounds__(512, 2)
lstm_main8(const XT* __restrict__ x, const unsigned short* __restrict__ Wt,
           const unsigned short* __restrict__ Wot, const float* __restrict__ bvec,
           const float* __restrict__ bo, float* __restrict__ out, int* __restrict__ xch) {
  __shared__ __align__(16) char lds[147456];  // 128K Wx + 8K h dbuf + 8K Wo
  const int bid = blockIdx.x;
  if (bid < 32) lstm_core<0, XT>(x, Wt, Wot, bvec, bo, out, xch, bid, lds);
  else          lstm_core<1, XT>(x, Wt, Wot, bvec, bo, out, xch, bid, lds);
}

extern "C" void kernel_launch(void* const* d_in, const int* in_sizes, int n_in,
                              void* d_out, int out_size, void* d_ws, size_t ws_size,
                              hipStream_t stream) {
  const float* x  = (const float*)d_in[0];
  const float* Wx = (const float*)d_in[1];
  const float* Wh = (const float*)d_in[2];
  const float* bv = (const float*)d_in[3];
  const float* Wo = (const float*)d_in[4];
  const float* bo = (const float*)d_in[5];

  char* ws = (char*)d_ws;
  size_t off = 0;
  int* xch = (int*)(ws + off);                          off += (size_t)262144 * 4;      // 1 MB
  unsigned short* Wt384 = (unsigned short*)(ws + off);  off += (size_t)1024 * 384 * 2;  // 768 KB
  unsigned short* Wot   = (unsigned short*)(ws + off);  off += (size_t)32 * 256 * 2;
  off = (off + 255) & ~(size_t)255;
  unsigned short* xb = (unsigned short*)(ws + off);
  const size_t need_xb = off + (size_t)BB * TT * FF * 2;  // ~69 MB total

  prep_w<<<1153, 384, 0, stream>>>(Wx, Wh, Wo, Wt384, Wot, xch);
  if (ws_size >= need_xb) {
    conv_x<<<32768, 256, 0, stream>>>(x, xb);
    lstm_main8<unsigned short><<<64, 512, 0, stream>>>(xb, Wt384, Wot, bv, bo, (float*)d_out, xch);
  } else {
    lstm_main8<float><<<64, 512, 0, stream>>>(x, Wt384, Wot, bv, bo, (float*)d_out, xch);
  }
}

// Round 10
// 1479.480 us; speedup vs baseline: 2.2469x; 2.2469x over previous
//
#include <hip/hip_runtime.h>
#include <stdint.h>

#define BB 512
#define TT 512
#define FF 128
#define UU 256

typedef float f32x4 __attribute__((ext_vector_type(4)));
typedef short short8 __attribute__((ext_vector_type(8)));
typedef int int4v __attribute__((ext_vector_type(4)));
typedef float float4v __attribute__((ext_vector_type(4)));
typedef unsigned short ushort4v __attribute__((ext_vector_type(4)));

__device__ __forceinline__ unsigned short f2bf(float f) {
  union { float f; uint32_t u; } v; v.f = f;
  uint32_t u = v.u;
  u += 0x7fffu + ((u >> 16) & 1u);
  return (unsigned short)(u >> 16);
}
__device__ __forceinline__ float fast_rcp(float x) { return __builtin_amdgcn_rcpf(x); }
__device__ __forceinline__ float sigmoidf_(float x) { return fast_rcp(1.f + __expf(-x)); }
__device__ __forceinline__ float tanhf_(float x) { return 1.f - 2.f * fast_rcp(1.f + __expf(2.f * x)); }

// ---- prep: W^T combined [1024 cols][384 k] bf16, Wo^T [32][256] bf16, zero xch ---------
__global__ void prep_w(const float* __restrict__ Wx, const float* __restrict__ Wh,
                       const float* __restrict__ Wo,
                       unsigned short* __restrict__ Wt, unsigned short* __restrict__ Wot,
                       int* __restrict__ xch) {
  int bidx = blockIdx.x;
  int tid = threadIdx.x; // 384
  if (bidx < 1024) {
    int n = bidx, k = tid;
    float v = (k < FF) ? Wx[(size_t)k * 1024 + n] : Wh[(size_t)(k - FF) * 1024 + n];
    Wt[(size_t)n * 384 + k] = f2bf(v);
  } else if (bidx == 1024) {
    for (int i = tid; i < 32 * 256; i += 384) {
      int o = i >> 8, u = i & 255;
      Wot[o * 256 + u] = f2bf(Wo[(size_t)u * 32 + o]);
    }
  } else {
    // zero the 1MB tagged-exchange buffer every launch (graph-replay safety)
    int base = (bidx - 1025) * 2048;  // 128 blocks x 2048 dwords
    for (int i = tid; i < 2048; i += 384) xch[base + i] = 0;
  }
}

// ---- x f32 -> bf16 ----------------------------------------------------------------------
__global__ void conv_x(const float* __restrict__ xf, unsigned short* __restrict__ xb) {
  size_t i = (size_t)blockIdx.x * 1024 + (size_t)threadIdx.x * 4;
  float4v v = *(const float4v*)(xf + i);
  ushort4v o;
  o.x = f2bf(v.x); o.y = f2bf(v.y); o.z = f2bf(v.z); o.w = f2bf(v.w);
  *(ushort4v*)(xb + i) = o;
}

__device__ __forceinline__ short8 load_xfrag(const unsigned short* p) {
  return *(const short8*)p;
}
__device__ __forceinline__ short8 load_xfrag(const float* p) {
  float4v lo = *(const float4v*)p;
  float4v hi = *(const float4v*)(p + 4);
  union { short8 v; unsigned short s[8]; } a;
  a.s[0] = f2bf(lo.x); a.s[1] = f2bf(lo.y); a.s[2] = f2bf(lo.z); a.s[3] = f2bf(lo.w);
  a.s[4] = f2bf(hi.x); a.s[5] = f2bf(hi.y); a.s[6] = f2bf(hi.z); a.s[7] = f2bf(hi.w);
  return a.v;
}

__device__ __forceinline__ void store_sc01(int* p, int v) {
  asm volatile("global_store_dword %0, %1, off sc0 sc1" :: "v"(p), "v"(v) : "memory");
}
__device__ __forceinline__ uint32_t pk2(int lo, int hi) {
  return ((uint32_t)lo >> 16) | ((uint32_t)hi & 0xffff0000u);
}

// ---- recurrent core: 2 CUs per m-tile; Wh in regs; Wx in LDS; single-leg tagged exchange
// xch tile (per mt, side, slot): [16 rows][128 units] tagged dwords ((bf16<<16)|step).
// tile dword base = ((mt*2 + side)*2 + slot)*2048.
// LDS: [0,128K) Wx frags; [128K,136K) own-h dbuf (2x4KB, XOR swz); [136K,140K) partner tile.
template <int HALF, typename XT>
__device__ __forceinline__ void lstm_core(const XT* __restrict__ x,
                                          const unsigned short* __restrict__ Wt,
                                          const float* __restrict__ bvec,
                                          unsigned short* __restrict__ h_hist,
                                          int* __restrict__ xch, int bid, char* lds) {
  const int mt = bid & 31;
  const int tid = threadIdx.x;
  const int w = tid >> 6, l = tid & 63;
  const int lr = l & 15, lhi = l >> 4;
  const int b0 = mt * 16;
  const int uloc = HALF * 128 + w * 16 + lr;  // global unit col in [0,256)
  char* hlds = lds + 131072;
  char* plds = lds + 139264;

  // stage Wx fragments (this wave's 16) into LDS — identity map
#pragma unroll
  for (int g = 0; g < 4; ++g)
#pragma unroll
    for (int kk = 0; kk < 4; ++kk) {
      const unsigned short* wp = Wt + (size_t)(g * 256 + uloc) * 384 + kk * 32 + 8 * lhi;
      *(short8*)(lds + ((size_t)((w * 16 + g * 4 + kk) * 64 + l)) * 16) = *(const short8*)wp;
    }

  // Wh fragments in registers: Bh[gate][kf], kf 0..7 over all 256 h-units
  short8 Bh[4][8];
#pragma unroll
  for (int g = 0; g < 4; ++g) {
    const unsigned short* wp = Wt + (size_t)(g * 256 + uloc) * 384 + FF + 8 * lhi;
#pragma unroll
    for (int kf = 0; kf < 8; ++kf) Bh[g][kf] = *(const short8*)(wp + kf * 32);
  }
  float bias[4];
#pragma unroll
  for (int g = 0; g < 4; ++g) bias[g] = bvec[g * 256 + uloc];
  float cst[4] = {0.f, 0.f, 0.f, 0.f};

  constexpr int kf_own = HALF * 4;
  constexpr int kf_par = (1 - HALF) * 4;

  const int rtile = (mt * 2 + (1 - HALF)) * 2;  // + slot
  const int wtile = (mt * 2 + HALF) * 2;

  // redistribute geometry: lane tid polls dwords [4*tid, 4*tid+4) of the partner tile
  const int prow = tid >> 5;               // row this lane redistributes
  const int pwbyte = (prow * 256 + (tid & 31) * 8) ^ ((prow & 7) << 4);

  // prologue x prefetch (t=0)
  short8 xa[4];
  {
    const XT* xp = x + ((size_t)(b0 + lr) * TT + 0) * FF + 8 * lhi;
#pragma unroll
    for (int kk = 0; kk < 4; ++kk) xa[kk] = load_xfrag(xp + kk * 32);
  }
  __syncthreads();  // Wx staging complete

#pragma unroll 1
  for (int t = 0; t < TT; ++t) {
    const int cur = t & 1, nxt = cur ^ 1;

    f32x4 acc[4];
#pragma unroll
    for (int g = 0; g < 4; ++g) { f32x4 a4 = {bias[g], bias[g], bias[g], bias[g]}; acc[g] = a4; }

    if (t > 0) {
      // own-half h(t) from LDS dbuf, 4 k-frags
      short8 ho[4];
#pragma unroll
      for (int ko = 0; ko < 4; ++ko) {
        const int byte = cur * 4096 + lr * 256 + ((ko * 64 + lhi * 16) ^ ((lr & 7) << 4));
        ho[ko] = *(const short8*)(hlds + byte);
      }
#pragma unroll
      for (int ko = 0; ko < 4; ++ko)
#pragma unroll
        for (int g = 0; g < 4; ++g)
          acc[g] = __builtin_amdgcn_mfma_f32_16x16x32_bf16(ho[ko], Bh[g][kf_own + ko], acc[g], 0, 0, 0);
    }

    // x-part: B-frags streamed from LDS
#pragma unroll
    for (int kk = 0; kk < 4; ++kk) {
      short8 bx[4];
#pragma unroll
      for (int g = 0; g < 4; ++g)
        bx[g] = *(const short8*)(lds + ((size_t)((w * 16 + g * 4 + kk) * 64 + l)) * 16);
#pragma unroll
      for (int g = 0; g < 4; ++g)
        acc[g] = __builtin_amdgcn_mfma_f32_16x16x32_bf16(xa[kk], bx[g], acc[g], 0, 0, 0);
    }

    // x prefetch for t+1 (overlaps the poll below)
    {
      const int tn = (t + 1 < TT) ? t + 1 : t;
      const XT* xp = x + ((size_t)(b0 + lr) * TT + tn) * FF + 8 * lhi;
#pragma unroll
      for (int kk = 0; kk < 4; ++kk) xa[kk] = load_xfrag(xp + kk * 32);
    }

    if (t > 0) {
      // single-leg tagged poll: each lane reads ITS 16B of partner h(t); data IS the flag
      const int* pp = xch + (rtile + cur) * 2048 + 4 * tid;
      int4v a;
      for (;;) {
        asm volatile("global_load_dwordx4 %0, %1, off sc0 sc1\n\ts_waitcnt vmcnt(0)"
                     : "=&v"(a) : "v"(pp) : "memory");
        int m = ((a.x ^ t) | (a.y ^ t) | (a.z ^ t) | (a.w ^ t)) & 0xffff;
        if (__all(m == 0)) break;
      }
      __builtin_amdgcn_sched_barrier(0);  // rule #18

      // redistribute through LDS (strip tags, 4 bf16 per lane)
      uint32_t d0 = pk2(a.x, a.y), d1 = pk2(a.z, a.w);
      *(uint64_t*)(plds + pwbyte) = ((uint64_t)d1 << 32) | d0;
      __syncthreads();  // barrier A: partner tile complete

      short8 hq[4];
#pragma unroll
      for (int ko = 0; ko < 4; ++ko) {
        const int byte = (lr * 256 + lhi * 16 + ko * 64) ^ ((lr & 7) << 4);
        hq[ko] = *(const short8*)(plds + byte);
      }
#pragma unroll
      for (int ko = 0; ko < 4; ++ko)
#pragma unroll
        for (int g = 0; g < 4; ++g)
          acc[g] = __builtin_amdgcn_mfma_f32_16x16x32_bf16(hq[ko], Bh[g][kf_par + ko], acc[g], 0, 0, 0);
    }

    // gates: thread holds i,f,g,o for rows b0+4*lhi+r, unit uloc
    unsigned short hs[4];
#pragma unroll
    for (int r = 0; r < 4; ++r) {
      float zi = acc[0][r], zf = acc[1][r], zg = acc[2][r], zo = acc[3][r];
      float si = sigmoidf_(zi), sf = sigmoidf_(zf), so = sigmoidf_(zo);
      float tg = tanhf_(zg);
      float cn = sf * cst[r] + si * tg;
      cst[r] = cn;
      hs[r] = f2bf(so * tanhf_(cn));
    }

    // publish h(t+1): LDS own dbuf + tagged xch dwords (no drain, no flag) + plain h_hist
    const int wb = (wtile + nxt) * 2048 + w * 16 + lr;
    unsigned short* hw = h_hist + (size_t)(t + 1) * (BB * UU) + uloc;
#pragma unroll
    for (int r = 0; r < 4; ++r) {
      const int row = 4 * lhi + r;
      const int byte = nxt * 4096 + row * 256 + (((w * 16 + lr) * 2) ^ ((row & 7) << 4));
      *(unsigned short*)(hlds + byte) = hs[r];
      store_sc01(xch + wb + row * 128, ((int)(uint32_t)hs[r] << 16) | (t + 1));
      hw[(size_t)(b0 + row) * UU] = hs[r];
    }

    __syncthreads();  // barrier B: protect LDS dbuf + partner tile across steps
  }
}

template <typename XT>
__global__ void __launch_bounds__(512, 2)
lstm_main10(const XT* __restrict__ x, const unsigned short* __restrict__ Wt,
            const float* __restrict__ bvec, unsigned short* __restrict__ h_hist,
            int* __restrict__ xch) {
  __shared__ __align__(16) char lds[143360];  // 128K Wx + 8K own dbuf + 4K partner (+pad)
  const int bid = blockIdx.x;
  if (bid < 32) lstm_core<0, XT>(x, Wt, bvec, h_hist, xch, bid, lds);
  else          lstm_core<1, XT>(x, Wt, bvec, h_hist, xch, bid, lds);
}

// ---- y = h @ Wo + bo --------------------------------------------------------------------
__global__ void __launch_bounds__(256)
y_gemm(const unsigned short* __restrict__ h_hist, const unsigned short* __restrict__ Wot,
       const float* __restrict__ bo, float* __restrict__ out) {
  int gw = (int)((blockIdx.x * 256 + threadIdx.x) >> 6);
  int l = threadIdx.x & 63;
  int lr = l & 15, lhi = l >> 4;
  int b = gw >> 5;
  int t0 = (gw & 31) * 16;

  short8 Wf[2][8];
#pragma unroll
  for (int n = 0; n < 2; ++n) {
    const unsigned short* wp = Wot + (n * 16 + lr) * 256 + 8 * lhi;
#pragma unroll
    for (int kk = 0; kk < 8; ++kk) Wf[n][kk] = *(const short8*)(wp + kk * 32);
  }
  f32x4 acc[2];
#pragma unroll
  for (int n = 0; n < 2; ++n) {
    float bb = bo[n * 16 + lr];
    f32x4 a4 = {bb, bb, bb, bb};
    acc[n] = a4;
  }
  const unsigned short* hp =
      h_hist + ((size_t)(t0 + lr + 1) * BB + b) * UU + 8 * lhi;
#pragma unroll
  for (int kk = 0; kk < 8; ++kk) {
    short8 a = *(const short8*)(hp + kk * 32);
#pragma unroll
    for (int n = 0; n < 2; ++n)
      acc[n] = __builtin_amdgcn_mfma_f32_16x16x32_bf16(a, Wf[n][kk], acc[n], 0, 0, 0);
  }
#pragma unroll
  for (int n = 0; n < 2; ++n) {
    int o = n * 16 + lr;
#pragma unroll
    for (int r = 0; r < 4; ++r) {
      int t = t0 + 4 * lhi + r;
      out[((size_t)b * TT + t) * 32 + o] = acc[n][r];
    }
  }
}

extern "C" void kernel_launch(void* const* d_in, const int* in_sizes, int n_in,
                              void* d_out, int out_size, void* d_ws, size_t ws_size,
                              hipStream_t stream) {
  const float* x  = (const float*)d_in[0];
  const float* Wx = (const float*)d_in[1];
  const float* Wh = (const float*)d_in[2];
  const float* bv = (const float*)d_in[3];
  const float* Wo = (const float*)d_in[4];
  const float* bo = (const float*)d_in[5];

  char* ws = (char*)d_ws;
  size_t off = 0;
  int* xch = (int*)(ws + off);                          off += (size_t)262144 * 4;       // 1 MB
  unsigned short* h_hist = (unsigned short*)(ws + off); off += (size_t)513 * BB * UU * 2; // 134.5 MB
  unsigned short* Wt384  = (unsigned short*)(ws + off); off += (size_t)1024 * 384 * 2;
  unsigned short* Wot    = (unsigned short*)(ws + off); off += (size_t)32 * 256 * 2;
  off = (off + 255) & ~(size_t)255;
  unsigned short* xb = (unsigned short*)(ws + off);
  const size_t need_xb = off + (size_t)BB * TT * FF * 2;  // ~203 MB total

  prep_w<<<1153, 384, 0, stream>>>(Wx, Wh, Wo, Wt384, Wot, xch);
  if (ws_size >= need_xb) {
    conv_x<<<32768, 256, 0, stream>>>(x, xb);
    lstm_main10<unsigned short><<<64, 512, 0, stream>>>(xb, Wt384, bv, h_hist, xch);
  } else {
    lstm_main10<float><<<64, 512, 0, stream>>>(x, Wt384, bv, h_hist, xch);
  }
  y_gemm<<<4096, 256, 0, stream>>>(h_hist, Wot, bo, (float*)d_out);
}